// Round 1
// 827.222 us; speedup vs baseline: 1.8235x; 1.8235x over previous
//
#include <hip/hip_runtime.h>

#define IN_HW 512
#define OUT_HW 1024
#define NB 32
#define NC 3
#define TOH 32
#define TOW 128
#define PATCH_H 24   // TOH/2 + 8
#define PATCH_W 72   // TOW/2 + 8
#define NTHREADS 256

// ---------------- sortable-key encoding for f32 atomics ----------------------
__device__ __forceinline__ unsigned enc_f(float f) {
  unsigned u = __float_as_uint(f);
  return (u & 0x80000000u) ? ~u : (u | 0x80000000u);
}
__device__ __forceinline__ float dec_f(unsigned k) {
  unsigned u = (k & 0x80000000u) ? (k ^ 0x80000000u) : ~k;
  return __uint_as_float(u);
}

// ---------------- hardcoded normalized Lanczos4 2x-upsample weights ----------
// Derived in f64: w(d)=sinc(d)sinc(d/4), phases d=3.75-j (even) / 3.25-j (odd),
// normalized to sum 1. W1 is the mirror of W0. Max abs error ~2e-6 -> output
// perturbation ~0.05 u8 levels; cannot change absmax class (trunc diff needs
// >1.0 float delta to reach 2).
#define LW_A -0.00397053f  /* |d|=3.75 */
#define LW_B  0.03146474f  /* |d|=2.75 */
#define LW_C -0.09165979f  /* |d|=1.75 */
#define LW_D  0.28268104f  /* |d|=0.75 */
#define LW_E  0.89337959f  /* |d|=0.25 */
#define LW_F -0.15228947f  /* |d|=1.25 */
#define LW_G  0.05544842f  /* |d|=2.25 */
#define LW_H -0.01505400f  /* |d|=3.25 */

// ---------------- kernel 0: init min/max key slots (ws is poisoned) ----------
__global__ void k_init(unsigned* __restrict__ maxk, unsigned* __restrict__ mink) {
  int i = threadIdx.x;
  if (i < NB) maxk[i] = 0u;
  else if (i < 2 * NB) mink[i - NB] = 0xFFFFFFFFu;
}

// ---------------- kernel 1: resize -> f32 into out buffer + min/max ----------
// Thread task: col-octet o = tid&15 (out cols 8o..8o+7), row-pair p = tid>>4
// (out rows 2p, 2p+1). Vertical resample for 12 contiguous columns (3 quads)
// into registers via ds_read_b128, then horizontal in registers. Weights are
// immediates. Output stored as raw f32 bits into the int32 output buffer.
__global__ __launch_bounds__(NTHREADS) void k_resize(
    const float* __restrict__ x, float* __restrict__ outf,
    unsigned* __restrict__ maxk, unsigned* __restrict__ mink) {
  __shared__ __align__(16) float patch[PATCH_H][PATCH_W];
  __shared__ float wred[8];
  const int tid = threadIdx.x;
  const int bc = blockIdx.z;
  const int oh0 = blockIdx.y * TOH, ow0 = blockIdx.x * TOW;
  const int row0 = (oh0 >> 1) - 4;
  const int col0 = (ow0 >> 1) - 4;
  const float* __restrict__ xchan = x + (size_t)bc * (IN_HW * IN_HW);

  const bool interior = (row0 >= 0) & (row0 + PATCH_H <= IN_HW) &
                        (col0 >= 0) & (col0 + PATCH_W <= IN_HW);
  if (interior) {
    // vectorized staging: 24 rows x 18 float4
    for (int e = tid; e < PATCH_H * (PATCH_W / 4); e += NTHREADS) {
      int pr = e / (PATCH_W / 4), pc4 = e - pr * (PATCH_W / 4);
      const float4 v = *reinterpret_cast<const float4*>(
          xchan + (size_t)(row0 + pr) * IN_HW + (col0 + 4 * pc4));
      *reinterpret_cast<float4*>(&patch[pr][4 * pc4]) = v;
    }
  } else {
    // border tiles: scalar with replicate clamp
    for (int e = tid; e < PATCH_H * PATCH_W; e += NTHREADS) {
      int pr = e / PATCH_W, pc = e - pr * PATCH_W;
      int gr = row0 + pr; gr = gr < 0 ? 0 : (gr > IN_HW - 1 ? IN_HW - 1 : gr);
      int gc = col0 + pc; gc = gc < 0 ? 0 : (gc > IN_HW - 1 ? IN_HW - 1 : gc);
      patch[pr][pc] = xchan[(size_t)gr * IN_HW + gc];
    }
  }
  __syncthreads();

  const int o = tid & 15;   // col octet
  const int p = tid >> 4;   // row pair (0..15)

  const float w0[8] = {LW_A, LW_B, LW_C, LW_D, LW_E, LW_F, LW_G, LW_H};
  const float w1[8] = {LW_H, LW_G, LW_F, LW_E, LW_D, LW_C, LW_B, LW_A};

  // vertical: ve = vert row 2p (taps patch[p..p+7], w0),
  //           vo = vert row 2p+1 (taps patch[p+1..p+8], w1); 12 cols = quads o..o+2
  float ve[12], vo[12];
#pragma unroll
  for (int c = 0; c < 12; ++c) { ve[c] = 0.f; vo[c] = 0.f; }
#pragma unroll
  for (int j = 0; j < 9; ++j) {
#pragma unroll
    for (int g = 0; g < 3; ++g) {
      const float4 t = *reinterpret_cast<const float4*>(&patch[p + j][4 * (o + g)]);
      const float tv[4] = {t.x, t.y, t.z, t.w};
#pragma unroll
      for (int c = 0; c < 4; ++c) {
        if (j < 8) ve[4 * g + c] = fmaf(w0[j], tv[c], ve[4 * g + c]);
        if (j > 0) vo[4 * g + c] = fmaf(w1[j - 1], tv[c], vo[4 * g + c]);
      }
    }
  }

  // horizontal: even out col 8o+2m taps v[m..m+7] (w0); odd taps v[m+1..m+8] (w1)
  float mx = -__builtin_inff(), mn = __builtin_inff();
  const size_t base = (size_t)bc * (OUT_HW * OUT_HW) +
                      (size_t)(oh0 + 2 * p) * OUT_HW + (ow0 + 8 * o);
#pragma unroll
  for (int row = 0; row < 2; ++row) {
    const float* v = row ? vo : ve;
    float px[8];
#pragma unroll
    for (int m = 0; m < 4; ++m) {
      float pe = 0.f, po = 0.f;
#pragma unroll
      for (int j = 0; j < 8; ++j) {
        pe = fmaf(w0[j], v[m + j], pe);
        po = fmaf(w1[j], v[m + 1 + j], po);
      }
      px[2 * m] = pe; px[2 * m + 1] = po;
    }
#pragma unroll
    for (int i = 0; i < 8; ++i) { mx = fmaxf(mx, px[i]); mn = fminf(mn, px[i]); }
    float* dst = outf + base + (size_t)row * OUT_HW;
    *reinterpret_cast<float4*>(dst)     = make_float4(px[0], px[1], px[2], px[3]);
    *reinterpret_cast<float4*>(dst + 4) = make_float4(px[4], px[5], px[6], px[7]);
  }

  // block min/max: wave shuffle reduce, then cross-wave via LDS
#pragma unroll
  for (int s = 32; s > 0; s >>= 1) {
    mx = fmaxf(mx, __shfl_xor(mx, s, 64));
    mn = fminf(mn, __shfl_xor(mn, s, 64));
  }
  if ((tid & 63) == 0) { wred[tid >> 6] = mx; wred[4 + (tid >> 6)] = mn; }
  __syncthreads();
  if (tid == 0) {
    float bmx = fmaxf(fmaxf(wred[0], wred[1]), fmaxf(wred[2], wred[3]));
    float bmn = fminf(fminf(wred[4], wred[5]), fminf(wred[6], wred[7]));
    int b = bc / NC;
    atomicMax(&maxk[b], enc_f(bmx));
    atomicMin(&mink[b], enc_f(bmn));
  }
}

// ---------------- kernel 2: in-place renorm f32 -> saturating int32 ----------
__device__ __forceinline__ int renorm1(float img, bool applies, float cA, float cB,
                                       float om_ott, float om_ubt) {
  const float ott = 1.0f / 255.0f;
  const float ubt = -10.0f / 255.0f;
  float v1 = (img > 1.0f) ? fmaf(img - 1.0f, cA, 1.0f - ott)
           : (img < 1.0f) ? img * om_ott : img;
  float v2 = (v1 < 0.0f) ? fmaf(v1, cB, ubt)
           : (v1 > 0.0f) ? v1 * om_ubt : v1;
  float y = (applies ? v2 : img) * 255.0f;
  int t = (int)y;                       // XLA f32->u8: trunc toward zero
  return t < 0 ? 0 : (t > 255 ? 255 : t);
}

__global__ __launch_bounds__(NTHREADS) void k_renorm(
    int* out, const unsigned* __restrict__ maxk, const unsigned* __restrict__ mink) {
  const int b = blockIdx.y;
  const float mx = dec_f(maxk[b]);
  const float mn = dec_f(mink[b]);
  const bool applies = (mx - mn) > 1.0f;
  const float ott = 1.0f / 255.0f;
  const float ubt = -10.0f / 255.0f;
  const float otr = mx - 1.0f;
  const float cA = ott / ((otr != 0.0f) ? otr : 1.0f);
  const float cB = ubt / ((mn != 0.0f) ? mn : 1.0f);
  const float om_ott = 1.0f - ott;
  const float om_ubt = 1.0f - ubt;

  const int n4 = NC * OUT_HW * OUT_HW / 4;          // 786432 float4 per image
  const size_t base4 = (size_t)b * n4;
  float4* pf = reinterpret_cast<float4*>(out);
  int4* pi = reinterpret_cast<int4*>(out);
  for (int i = blockIdx.x * NTHREADS + threadIdx.x; i < n4; i += gridDim.x * NTHREADS) {
    float4 v = pf[base4 + i];
    int4 r;
    r.x = renorm1(v.x, applies, cA, cB, om_ott, om_ubt);
    r.y = renorm1(v.y, applies, cA, cB, om_ott, om_ubt);
    r.z = renorm1(v.z, applies, cA, cB, om_ott, om_ubt);
    r.w = renorm1(v.w, applies, cA, cB, om_ott, om_ubt);
    pi[base4 + i] = r;
  }
}

extern "C" void kernel_launch(void* const* d_in, const int* in_sizes, int n_in,
                              void* d_out, int out_size, void* d_ws, size_t ws_size,
                              hipStream_t stream) {
  const float* x = (const float*)d_in[0];
  unsigned* maxk = (unsigned*)d_ws;
  unsigned* mink = maxk + NB;

  hipLaunchKernelGGL(k_init, dim3(1), dim3(64), 0, stream, maxk, mink);
  dim3 grid(OUT_HW / TOW, OUT_HW / TOH, NB * NC);
  hipLaunchKernelGGL(k_resize, grid, dim3(NTHREADS), 0, stream,
                     x, (float*)d_out, maxk, mink);
  hipLaunchKernelGGL(k_renorm, dim3(512, NB), dim3(NTHREADS), 0, stream,
                     (int*)d_out, maxk, mink);
}

// Round 2
// 815.277 us; speedup vs baseline: 1.8502x; 1.0147x over previous
//
#include <hip/hip_runtime.h>

#define IN_HW 512
#define OUT_HW 1024
#define NB 32
#define NC 3
#define TOH 32
#define TOW 128
#define PATCH_H 24   // TOH/2 + 8
#define PATCH_W 72   // TOW/2 + 8
#define NTHREADS 256

// ---------------- sortable-key encoding for f32 atomics ----------------------
__device__ __forceinline__ unsigned enc_f(float f) {
  unsigned u = __float_as_uint(f);
  return (u & 0x80000000u) ? ~u : (u | 0x80000000u);
}
__device__ __forceinline__ float dec_f(unsigned k) {
  unsigned u = (k & 0x80000000u) ? (k ^ 0x80000000u) : ~k;
  return __uint_as_float(u);
}

// ---------------- hardcoded normalized Lanczos4 2x-upsample weights ----------
// Derived in f64: w(d)=sinc(d)sinc(d/4), phases d=3.75-j (even) / 3.25-j (odd),
// normalized to sum 1. W1 is the mirror of W0. Max abs error ~2e-6 -> output
// perturbation ~0.05 u8 levels; cannot change absmax class (trunc diff needs
// >1.0 float delta to reach 2).
#define LW_A -0.00397053f  /* |d|=3.75 */
#define LW_B  0.03146474f  /* |d|=2.75 */
#define LW_C -0.09165979f  /* |d|=1.75 */
#define LW_D  0.28268104f  /* |d|=0.75 */
#define LW_E  0.89337959f  /* |d|=0.25 */
#define LW_F -0.15228947f  /* |d|=1.25 */
#define LW_G  0.05544842f  /* |d|=2.25 */
#define LW_H -0.01505400f  /* |d|=3.25 */

// ---------------- kernel 0: init min/max key slots (ws is poisoned) ----------
__global__ void k_init(unsigned* __restrict__ maxk, unsigned* __restrict__ mink) {
  int i = threadIdx.x;
  if (i < NB) maxk[i] = 0u;
  else if (i < 2 * NB) mink[i - NB] = 0xFFFFFFFFu;
}

// ---------------- kernel 1: resize -> f32 into out buffer + min/max ----------
// (unchanged from previous round: 331 us, proven)
__global__ __launch_bounds__(NTHREADS) void k_resize(
    const float* __restrict__ x, float* __restrict__ outf,
    unsigned* __restrict__ maxk, unsigned* __restrict__ mink) {
  __shared__ __align__(16) float patch[PATCH_H][PATCH_W];
  __shared__ float wred[8];
  const int tid = threadIdx.x;
  const int bc = blockIdx.z;
  const int oh0 = blockIdx.y * TOH, ow0 = blockIdx.x * TOW;
  const int row0 = (oh0 >> 1) - 4;
  const int col0 = (ow0 >> 1) - 4;
  const float* __restrict__ xchan = x + (size_t)bc * (IN_HW * IN_HW);

  const bool interior = (row0 >= 0) & (row0 + PATCH_H <= IN_HW) &
                        (col0 >= 0) & (col0 + PATCH_W <= IN_HW);
  if (interior) {
    // vectorized staging: 24 rows x 18 float4
    for (int e = tid; e < PATCH_H * (PATCH_W / 4); e += NTHREADS) {
      int pr = e / (PATCH_W / 4), pc4 = e - pr * (PATCH_W / 4);
      const float4 v = *reinterpret_cast<const float4*>(
          xchan + (size_t)(row0 + pr) * IN_HW + (col0 + 4 * pc4));
      *reinterpret_cast<float4*>(&patch[pr][4 * pc4]) = v;
    }
  } else {
    // border tiles: scalar with replicate clamp
    for (int e = tid; e < PATCH_H * PATCH_W; e += NTHREADS) {
      int pr = e / PATCH_W, pc = e - pr * PATCH_W;
      int gr = row0 + pr; gr = gr < 0 ? 0 : (gr > IN_HW - 1 ? IN_HW - 1 : gr);
      int gc = col0 + pc; gc = gc < 0 ? 0 : (gc > IN_HW - 1 ? IN_HW - 1 : gc);
      patch[pr][pc] = xchan[(size_t)gr * IN_HW + gc];
    }
  }
  __syncthreads();

  const int o = tid & 15;   // col octet
  const int p = tid >> 4;   // row pair (0..15)

  const float w0[8] = {LW_A, LW_B, LW_C, LW_D, LW_E, LW_F, LW_G, LW_H};
  const float w1[8] = {LW_H, LW_G, LW_F, LW_E, LW_D, LW_C, LW_B, LW_A};

  // vertical: ve = vert row 2p (taps patch[p..p+7], w0),
  //           vo = vert row 2p+1 (taps patch[p+1..p+8], w1); 12 cols = quads o..o+2
  float ve[12], vo[12];
#pragma unroll
  for (int c = 0; c < 12; ++c) { ve[c] = 0.f; vo[c] = 0.f; }
#pragma unroll
  for (int j = 0; j < 9; ++j) {
#pragma unroll
    for (int g = 0; g < 3; ++g) {
      const float4 t = *reinterpret_cast<const float4*>(&patch[p + j][4 * (o + g)]);
      const float tv[4] = {t.x, t.y, t.z, t.w};
#pragma unroll
      for (int c = 0; c < 4; ++c) {
        if (j < 8) ve[4 * g + c] = fmaf(w0[j], tv[c], ve[4 * g + c]);
        if (j > 0) vo[4 * g + c] = fmaf(w1[j - 1], tv[c], vo[4 * g + c]);
      }
    }
  }

  // horizontal: even out col 8o+2m taps v[m..m+7] (w0); odd taps v[m+1..m+8] (w1)
  float mx = -__builtin_inff(), mn = __builtin_inff();
  const size_t base = (size_t)bc * (OUT_HW * OUT_HW) +
                      (size_t)(oh0 + 2 * p) * OUT_HW + (ow0 + 8 * o);
#pragma unroll
  for (int row = 0; row < 2; ++row) {
    const float* v = row ? vo : ve;
    float px[8];
#pragma unroll
    for (int m = 0; m < 4; ++m) {
      float pe = 0.f, po = 0.f;
#pragma unroll
      for (int j = 0; j < 8; ++j) {
        pe = fmaf(w0[j], v[m + j], pe);
        po = fmaf(w1[j], v[m + 1 + j], po);
      }
      px[2 * m] = pe; px[2 * m + 1] = po;
    }
#pragma unroll
    for (int i = 0; i < 8; ++i) { mx = fmaxf(mx, px[i]); mn = fminf(mn, px[i]); }
    float* dst = outf + base + (size_t)row * OUT_HW;
    *reinterpret_cast<float4*>(dst)     = make_float4(px[0], px[1], px[2], px[3]);
    *reinterpret_cast<float4*>(dst + 4) = make_float4(px[4], px[5], px[6], px[7]);
  }

  // block min/max: wave shuffle reduce, then cross-wave via LDS
#pragma unroll
  for (int s = 32; s > 0; s >>= 1) {
    mx = fmaxf(mx, __shfl_xor(mx, s, 64));
    mn = fminf(mn, __shfl_xor(mn, s, 64));
  }
  if ((tid & 63) == 0) { wred[tid >> 6] = mx; wred[4 + (tid >> 6)] = mn; }
  __syncthreads();
  if (tid == 0) {
    float bmx = fmaxf(fmaxf(wred[0], wred[1]), fmaxf(wred[2], wred[3]));
    float bmn = fminf(fminf(wred[4], wred[5]), fminf(wred[6], wred[7]));
    int b = bc / NC;
    atomicMax(&maxk[b], enc_f(bmx));
    atomicMin(&mink[b], enc_f(bmn));
  }
}

// ---------------- kernel 2: in-place renorm f32 -> saturating int32 ----------
// ONE float4 -> int4 per thread. No grid-stride loop: the previous version's
// 6-iteration loop over an aliased in-place buffer serialized each thread to
// one ~900cy HBM round-trip per iteration (compiler can't hoist the next load
// above the prior store on the same pointer). One item per thread issues the
// single load immediately -> chip-wide MLP bounded only by occupancy.
__device__ __forceinline__ int renorm1(float img, bool applies, float cA, float cB,
                                       float om_ott, float om_ubt) {
  const float ott = 1.0f / 255.0f;
  const float ubt = -10.0f / 255.0f;
  float v1 = (img > 1.0f) ? fmaf(img - 1.0f, cA, 1.0f - ott)
           : (img < 1.0f) ? img * om_ott : img;
  float v2 = (v1 < 0.0f) ? fmaf(v1, cB, ubt)
           : (v1 > 0.0f) ? v1 * om_ubt : v1;
  float y = (applies ? v2 : img) * 255.0f;
  int t = (int)y;                       // XLA f32->u8: trunc toward zero
  return t < 0 ? 0 : (t > 255 ? 255 : t);
}

#define N4_PER_IMG (NC * OUT_HW * OUT_HW / 4)   // 786432 float4 per image

__global__ __launch_bounds__(NTHREADS) void k_renorm(
    int* out, const unsigned* __restrict__ maxk, const unsigned* __restrict__ mink) {
  const int b = blockIdx.y;
  const float mx = dec_f(maxk[b]);
  const float mn = dec_f(mink[b]);
  const bool applies = (mx - mn) > 1.0f;
  const float ott = 1.0f / 255.0f;
  const float ubt = -10.0f / 255.0f;
  const float otr = mx - 1.0f;
  const float cA = ott / ((otr != 0.0f) ? otr : 1.0f);
  const float cB = ubt / ((mn != 0.0f) ? mn : 1.0f);
  const float om_ott = 1.0f - ott;
  const float om_ubt = 1.0f - ubt;

  const size_t idx = (size_t)b * N4_PER_IMG +
                     (size_t)blockIdx.x * NTHREADS + threadIdx.x;
  const float4 v = reinterpret_cast<const float4*>(out)[idx];
  int4 r;
  r.x = renorm1(v.x, applies, cA, cB, om_ott, om_ubt);
  r.y = renorm1(v.y, applies, cA, cB, om_ott, om_ubt);
  r.z = renorm1(v.z, applies, cA, cB, om_ott, om_ubt);
  r.w = renorm1(v.w, applies, cA, cB, om_ott, om_ubt);
  reinterpret_cast<int4*>(out)[idx] = r;
}

extern "C" void kernel_launch(void* const* d_in, const int* in_sizes, int n_in,
                              void* d_out, int out_size, void* d_ws, size_t ws_size,
                              hipStream_t stream) {
  const float* x = (const float*)d_in[0];
  unsigned* maxk = (unsigned*)d_ws;
  unsigned* mink = maxk + NB;

  hipLaunchKernelGGL(k_init, dim3(1), dim3(64), 0, stream, maxk, mink);
  dim3 grid(OUT_HW / TOW, OUT_HW / TOH, NB * NC);
  hipLaunchKernelGGL(k_resize, grid, dim3(NTHREADS), 0, stream,
                     x, (float*)d_out, maxk, mink);
  hipLaunchKernelGGL(k_renorm, dim3(N4_PER_IMG / NTHREADS, NB), dim3(NTHREADS),
                     0, stream, (int*)d_out, maxk, mink);
}